// Round 2
// baseline (1457.570 us; speedup 1.0000x reference)
//
#include <hip/hip_runtime.h>

typedef __attribute__((ext_vector_type(8))) unsigned short u16x8;

__device__ __forceinline__ float bf2f(unsigned short u) {
    union { unsigned int i; float f; } c; c.i = ((unsigned int)u) << 16; return c.f;
}
__device__ __forceinline__ unsigned short f2bf(float f) {
    union { float f; unsigned int i; } c; c.f = f;
    unsigned int u = c.i;
    return (unsigned short)((u + 0x7fffu + ((u >> 16) & 1u)) >> 16);
}

// ---------------------------------------------------------------------------
// Dtype probe: decide whether inputs are packed bf16 (flag=1) or fp32 (flag=0).
// For bf16 data, the LOW ushort of each 32-bit word is a bf16 value of a
// ~N(0,1/32) weight -> exponent bits in [0x58,0x80] essentially always.
// For fp32 data those bits are mantissa bits -> ~uniform (~16% in window).
// ---------------------------------------------------------------------------
__global__ void detect_dtype(const unsigned int* __restrict__ w, int* __restrict__ flag) {
    const int tid = threadIdx.x;  // 64 threads
    int cnt = 0;
    for (int i = tid; i < 1024; i += 64) {
        unsigned int v = w[i];
        unsigned int e = (v >> 7) & 0xFFu;
        cnt += (e >= 0x58u && e <= 0x80u) ? 1 : 0;
    }
#pragma unroll
    for (int off = 32; off; off >>= 1) cnt += __shfl_xor(cnt, off);
    if (tid == 0) *flag = (cnt >= 512) ? 1 : 0;
}

// ---------------------------------------------------------------------------
// GEMM (NT): out[m][n] = sum_k A[m][k] * W[n][k] + bias[n]
// A: M x K row-major, W: N x K row-major. Input dtype per runtime flag.
// MODE 0: scatter fp32 to q/k/v buffers laid out (B=2, H=16, N=2048, D=64)
// MODE 1: A is always bf16 (internal attn-out); writes out (bf16 or fp32 per flag)
// Tile: 128x128x16, 256 threads, 8x8 micro-tile per thread.
// ---------------------------------------------------------------------------
template<int MODE>
__global__ __launch_bounds__(256) void gemm_nt(
    const void* __restrict__ A,
    const void* __restrict__ W,
    const void* __restrict__ bias,
    const int* __restrict__ flag,
    float* __restrict__ qo, float* __restrict__ ko, float* __restrict__ vo,
    void* __restrict__ outp,
    int M, int N, int K)
{
    __shared__ float As[16][128];   // [k][m]
    __shared__ float Bs[16][128];   // [k][n]
    const bool fbf = (*flag != 0);               // inputs are bf16?
    const bool abf = (MODE == 1) ? true : fbf;   // A operand bf16?

    const int tid = threadIdx.x;
    const int m0 = blockIdx.y * 128;
    const int n0 = blockIdx.x * 128;
    const int tx = tid & 15, ty = tid >> 4;
    const int lr = tid >> 1;          // 0..127 tile row
    const int lc = (tid & 1) * 8;     // 0 or 8 within k-slab

    float acc[8][8];
#pragma unroll
    for (int i = 0; i < 8; i++)
#pragma unroll
        for (int j = 0; j < 8; j++) acc[i][j] = 0.f;

    for (int k0 = 0; k0 < K; k0 += 16) {
        const size_t aoff = (size_t)(m0 + lr) * K + lc + k0;
        const size_t woff = (size_t)(n0 + lr) * K + lc + k0;
        float av[8], wv[8];
        if (abf) {
            u16x8 u = *(const u16x8*)((const unsigned short*)A + aoff);
#pragma unroll
            for (int i = 0; i < 8; i++) av[i] = bf2f(u[i]);
        } else {
            const float* p = (const float*)A + aoff;
            float4 f0 = *(const float4*)p, f1 = *(const float4*)(p + 4);
            av[0]=f0.x; av[1]=f0.y; av[2]=f0.z; av[3]=f0.w;
            av[4]=f1.x; av[5]=f1.y; av[6]=f1.z; av[7]=f1.w;
        }
        if (fbf) {
            u16x8 u = *(const u16x8*)((const unsigned short*)W + woff);
#pragma unroll
            for (int i = 0; i < 8; i++) wv[i] = bf2f(u[i]);
        } else {
            const float* p = (const float*)W + woff;
            float4 f0 = *(const float4*)p, f1 = *(const float4*)(p + 4);
            wv[0]=f0.x; wv[1]=f0.y; wv[2]=f0.z; wv[3]=f0.w;
            wv[4]=f1.x; wv[5]=f1.y; wv[6]=f1.z; wv[7]=f1.w;
        }
        __syncthreads();               // prior iteration's LDS reads done
#pragma unroll
        for (int i = 0; i < 8; i++) {
            As[lc + i][lr] = av[i];
            Bs[lc + i][lr] = wv[i];
        }
        __syncthreads();
#pragma unroll
        for (int kk = 0; kk < 16; kk++) {
            float a[8], b[8];
            *(float4*)&a[0] = *(const float4*)&As[kk][ty * 8];
            *(float4*)&a[4] = *(const float4*)&As[kk][ty * 8 + 4];
            *(float4*)&b[0] = *(const float4*)&Bs[kk][tx * 4];
            *(float4*)&b[4] = *(const float4*)&Bs[kk][tx * 4 + 64];
#pragma unroll
            for (int i = 0; i < 8; i++)
#pragma unroll
                for (int j = 0; j < 8; j++)
                    acc[i][j] += a[i] * b[j];
        }
    }

#pragma unroll
    for (int i = 0; i < 8; i++) {
        const int gm = m0 + ty * 8 + i;
        const int b_ = gm >> 11, npos = gm & 2047;   // M = 2*2048
#pragma unroll
        for (int j = 0; j < 8; j++) {
            const int gc = n0 + tx * 4 + (j & 3) + ((j >> 2) * 64);
            const float bv = fbf ? bf2f(((const unsigned short*)bias)[gc])
                                 : ((const float*)bias)[gc];
            const float val = acc[i][j] + bv;
            if (MODE == 0) {
                const int t3 = gc >> 10, rem = gc & 1023;
                const int h = rem >> 6, d = rem & 63;
                float* dst = (t3 == 0) ? qo : ((t3 == 1) ? ko : vo);
                dst[(((size_t)(b_ * 16 + h)) * 2048 + npos) * 64 + d] = val;
            } else {
                const size_t oidx = (size_t)gm * N + gc;
                if (fbf) ((unsigned short*)outp)[oidx] = f2bf(val);
                else     ((float*)outp)[oidx] = val;
            }
        }
    }
}

// ---------------------------------------------------------------------------
// RMSNorm + segmented RoPE, in place on fp32 q/k buffers (B,H,N,D), D=64.
// One wave (64 lanes) per row; 131072 rows total (q then k).
// ---------------------------------------------------------------------------
__global__ __launch_bounds__(256) void norm_rope(
    float* __restrict__ q, float* __restrict__ k,
    const void* __restrict__ qw, const void* __restrict__ kw,
    const int* __restrict__ flag)
{
    const bool fbf = (*flag != 0);
    const int gwave = blockIdx.x * 4 + (threadIdx.x >> 6);
    const int lane = threadIdx.x & 63;
    const int which = gwave >> 16;       // 65536 rows per tensor
    const int row = gwave & 65535;
    float* buf = which ? k : q;
    const void* w = which ? kw : qw;
    const float wval = fbf ? bf2f(((const unsigned short*)w)[lane])
                           : ((const float*)w)[lane];

    float val = buf[(size_t)row * 64 + lane];
    float ss = val * val;
#pragma unroll
    for (int off = 32; off; off >>= 1) ss += __shfl_xor(ss, off);
    const float r = rsqrtf(ss * (1.0f / 64.0f) + 1e-6f);
    float nv = val * r * wval;

    const int npos = row & 2047;
    float outv = nv;
    if (npos < 1536) {  // wave-uniform branch
        const int p = (npos < 1024) ? npos : (npos - 1024);
        const int i = lane & 31;
        // inv_freq = 10000^(-2i/64) = 2^(-2i*log2(10000)/64)
        const float inv = exp2f(-(float)(2 * i) * (13.287712379549449f / 64.0f));
        const float ang = (float)p * inv;
        const float c = cosf(ang), s = sinf(ang);
        const float partner = __shfl_xor(nv, 32);
        outv = (lane < 32) ? (nv * c - partner * s) : (nv * c + partner * s);
    }
    buf[(size_t)row * 64 + lane] = outv;
}

// ---------------------------------------------------------------------------
// Flash attention, fp32 vector. One block = one (b,h) x 32 q-rows.
// 256 threads: (qr = t>>3, kg = t&7); 8 lanes per q-row (intra-wave groups).
// KV tiles of 32 keys in LDS. Online softmax. Output bf16 (B,N,H*D).
// ---------------------------------------------------------------------------
__global__ __launch_bounds__(256) void flash_attn(
    const float* __restrict__ qb, const float* __restrict__ kb,
    const float* __restrict__ vb, unsigned short* __restrict__ ao)
{
    __shared__ float Qs[32][68];
    __shared__ float Ks[32][68];
    __shared__ float Vs[32][68];
    __shared__ float Ps[32][36];

    const int bh = blockIdx.y;               // 0..31  (= b*16 + h)
    const int q0 = blockIdx.x * 32;
    const int tid = threadIdx.x;
    const int qr = tid >> 3, kg = tid & 7;
    const int ldr = tid >> 3, ldc = (tid & 7) * 8;
    const size_t base = (size_t)bh * 2048 * 64;

    {   // load Q tile
        const float* src = qb + base + (size_t)(q0 + ldr) * 64 + ldc;
        float4 a0 = *(const float4*)src, a1 = *(const float4*)(src + 4);
        *(float4*)&Qs[ldr][ldc] = a0; *(float4*)&Qs[ldr][ldc + 4] = a1;
    }

    float m = -INFINITY, l = 0.f;
    float acc[8];
#pragma unroll
    for (int j = 0; j < 8; j++) acc[j] = 0.f;

    for (int kt = 0; kt < 64; kt++) {
        const float* ksrc = kb + base + (size_t)(kt * 32 + ldr) * 64 + ldc;
        const float* vsrc = vb + base + (size_t)(kt * 32 + ldr) * 64 + ldc;
        float4 k0v = *(const float4*)ksrc, k1v = *(const float4*)(ksrc + 4);
        float4 v0v = *(const float4*)vsrc, v1v = *(const float4*)(vsrc + 4);
        __syncthreads();    // prior iteration's LDS reads complete
        *(float4*)&Ks[ldr][ldc] = k0v; *(float4*)&Ks[ldr][ldc + 4] = k1v;
        *(float4*)&Vs[ldr][ldc] = v0v; *(float4*)&Vs[ldr][ldc + 4] = v1v;
        __syncthreads();

        float s[4];
#pragma unroll
        for (int kk = 0; kk < 4; kk++) {
            const int key = kg + 8 * kk;
            float d0 = 0.f;
#pragma unroll
            for (int d4 = 0; d4 < 16; d4++) {
                float4 qa = *(const float4*)&Qs[qr][d4 * 4];
                float4 ka = *(const float4*)&Ks[key][d4 * 4];
                d0 += qa.x * ka.x + qa.y * ka.y + qa.z * ka.z + qa.w * ka.w;
            }
            s[kk] = d0 * 0.125f;   // 1/sqrt(64)
        }
        float tmax = fmaxf(fmaxf(s[0], s[1]), fmaxf(s[2], s[3]));
#pragma unroll
        for (int off = 1; off < 8; off <<= 1) tmax = fmaxf(tmax, __shfl_xor(tmax, off));
        const float mnew = fmaxf(m, tmax);
        const float alpha = __expf(m - mnew);
        float rs = 0.f;
#pragma unroll
        for (int kk = 0; kk < 4; kk++) {
            const float p = __expf(s[kk] - mnew);
            rs += p;
            Ps[qr][kg + 8 * kk] = p;     // same-wave write/read
        }
#pragma unroll
        for (int off = 1; off < 8; off <<= 1) rs += __shfl_xor(rs, off);
        l = l * alpha + rs;
        m = mnew;
#pragma unroll
        for (int j = 0; j < 8; j++) acc[j] *= alpha;

#pragma unroll 4
        for (int kk2 = 0; kk2 < 32; kk2++) {
            const float p = Ps[qr][kk2];
            float4 va = *(const float4*)&Vs[kk2][kg * 8];
            float4 vv = *(const float4*)&Vs[kk2][kg * 8 + 4];
            acc[0] += p * va.x; acc[1] += p * va.y;
            acc[2] += p * va.z; acc[3] += p * va.w;
            acc[4] += p * vv.x; acc[5] += p * vv.y;
            acc[6] += p * vv.z; acc[7] += p * vv.w;
        }
    }

    const float inv_l = 1.0f / l;
    const int h = bh & 15, b_ = bh >> 4;
    const size_t orow = ((size_t)(b_ * 2048 + q0 + qr)) * 1024 + h * 64 + kg * 8;
    u16x8 ov;
#pragma unroll
    for (int j = 0; j < 8; j++) ov[j] = f2bf(acc[j] * inv_l);
    *(u16x8*)(ao + orow) = ov;
}

// ---------------------------------------------------------------------------
extern "C" void kernel_launch(void* const* d_in, const int* in_sizes, int n_in,
                              void* d_out, int out_size, void* d_ws, size_t ws_size,
                              hipStream_t stream)
{
    const void* x      = d_in[0];
    const void* qkv_w  = d_in[1];
    const void* qkv_b  = d_in[2];
    const void* qn_w   = d_in[3];
    const void* kn_w   = d_in[4];
    const void* proj_w = d_in[5];
    const void* proj_b = d_in[6];

    // ws layout: [flag: 256B] [q fp32 16MB] [k fp32 16MB] [v fp32 16MB] [ao bf16 8MB]
    char* base = (char*)d_ws;
    int* flag = (int*)base;
    float* qbuf = (float*)(base + 256);
    float* kbuf = qbuf + 4194304;
    float* vbuf = kbuf + 4194304;
    unsigned short* ao = (unsigned short*)(vbuf + 4194304);

    // 0) probe input dtype (writes flag; every launch — ws is re-poisoned)
    detect_dtype<<<1, 64, 0, stream>>>((const unsigned int*)qkv_w, flag);

    // 1) QKV projection: (4096 x 1024) @ (3072 x 1024)^T + bias -> q/k/v fp32
    gemm_nt<0><<<dim3(24, 32), 256, 0, stream>>>(
        x, qkv_w, qkv_b, flag, qbuf, kbuf, vbuf, nullptr, 4096, 3072, 1024);

    // 2) RMSNorm + segmented RoPE on q and k (in place, fp32)
    norm_rope<<<32768, 256, 0, stream>>>(qbuf, kbuf, qn_w, kn_w, flag);

    // 3) flash attention -> ao (B,N,C) bf16
    flash_attn<<<dim3(64, 32), 256, 0, stream>>>(qbuf, kbuf, vbuf, ao);

    // 4) output projection: (4096 x 1024) @ (1024 x 1024)^T + bias -> d_out
    gemm_nt<1><<<dim3(8, 32), 256, 0, stream>>>(
        ao, proj_w, proj_b, flag, nullptr, nullptr, nullptr, d_out, 4096, 1024, 1024);
}

// Round 3
// 261.922 us; speedup vs baseline: 5.5649x; 5.5649x over previous
//
#include <hip/hip_runtime.h>

typedef __attribute__((ext_vector_type(8))) short short8;
typedef __attribute__((ext_vector_type(4))) float f32x4;

__device__ __forceinline__ float bf2f(unsigned short u) {
    union { unsigned int i; float f; } c; c.i = ((unsigned int)u) << 16; return c.f;
}
__device__ __forceinline__ unsigned short f2bf(float f) {
    union { float f; unsigned int i; } c; c.f = f;
    unsigned int u = c.i;
    return (unsigned short)((u + 0x7fffu + ((u >> 16) & 1u)) >> 16);
}

// async global->LDS, 16B per lane. LDS dest = wave-uniform base + lane*16.
__device__ __forceinline__ void glds16(const void* g, void* l) {
    __builtin_amdgcn_global_load_lds(
        (const __attribute__((address_space(1))) unsigned int*)g,
        (__attribute__((address_space(3))) unsigned int*)l, 16, 0, 0);
}

// ---------------------------------------------------------------------------
// fp32 -> bf16 convert (n4 = n/4)
// ---------------------------------------------------------------------------
__global__ __launch_bounds__(256) void cvt_bf16(
    const float* __restrict__ s, unsigned short* __restrict__ d, int n4)
{
    int i = blockIdx.x * 256 + threadIdx.x;
    if (i < n4) {
        float4 v = ((const float4*)s)[i];
        ushort4 o;
        o.x = f2bf(v.x); o.y = f2bf(v.y); o.z = f2bf(v.z); o.w = f2bf(v.w);
        ((ushort4*)d)[i] = o;
    }
}

// ---------------------------------------------------------------------------
// softmax bound: scores <= 8 * max|qn_w| * max|kn_w|  (RMSNorm => |q̂|2 <= 8*max|w|,
// RoPE is norm-preserving). Stores MB2 = bound * log2(e) for exp2-based softmax.
// ---------------------------------------------------------------------------
__global__ void wmax_k(const float* __restrict__ qw, const float* __restrict__ kw,
                       float* __restrict__ mb2)
{
    int l = threadIdx.x;  // 64 == D
    float a = fabsf(qw[l]), b = fabsf(kw[l]);
#pragma unroll
    for (int off = 32; off; off >>= 1) {
        a = fmaxf(a, __shfl_xor(a, off));
        b = fmaxf(b, __shfl_xor(b, off));
    }
    if (l == 0) *mb2 = 8.0f * a * b * 1.4426950408889634f;
}

// ---------------------------------------------------------------------------
// bf16 MFMA GEMM (NT): C[m][n] = sum_k A[m][k]*W[n][k] + bias[n]
// 128x128 tile, BK=32, 256 thr (4 waves, 2x2 wave grid, 4x4 mfma tiles each).
// LDS chunks XOR-swizzled by ((row>>1)&3) to kill ds_read_b128 bank conflicts.
// MODE 0: scatter q,k -> bf16 [bh][n][64]; v -> bf16 transposed [bh][64][n]
// MODE 1: out fp32 row-major (M x 1024)
// ---------------------------------------------------------------------------
template<int MODE>
__global__ __launch_bounds__(256) void gemm_mfma(
    const unsigned short* __restrict__ A,
    const unsigned short* __restrict__ W,
    const float* __restrict__ bias,
    unsigned short* __restrict__ qb, unsigned short* __restrict__ kb,
    unsigned short* __restrict__ vt,
    float* __restrict__ outp, int K)
{
    __shared__ unsigned short As[128 * 32];
    __shared__ unsigned short Ws[128 * 32];
    const int tid = threadIdx.x;
    const int w = tid >> 6, l = tid & 63, quad = l >> 4, low = l & 15;
    const int m0 = blockIdx.y * 128, n0 = blockIdx.x * 128;
    const int wm = w >> 1, wn = w & 1;

    f32x4 acc[4][4];
#pragma unroll
    for (int i = 0; i < 4; i++)
#pragma unroll
        for (int j = 0; j < 4; j++) acc[i][j] = (f32x4){0.f, 0.f, 0.f, 0.f};

    const int r1 = tid >> 2, p1 = tid & 3;
    const int c1 = p1 ^ ((r1 >> 1) & 3);
    const int r2 = r1 + 64;
    const int c2 = p1 ^ ((r2 >> 1) & 3);
    const unsigned short* ga1 = A + (size_t)(m0 + r1) * K + c1 * 8;
    const unsigned short* ga2 = A + (size_t)(m0 + r2) * K + c2 * 8;
    const unsigned short* gw1 = W + (size_t)(n0 + r1) * K + c1 * 8;
    const unsigned short* gw2 = W + (size_t)(n0 + r2) * K + c2 * 8;
    char* lA = (char*)As + (w << 10);
    char* lW = (char*)Ws + (w << 10);

    for (int k0 = 0; k0 < K; k0 += 32) {
        __syncthreads();
        glds16(ga1 + k0, lA);
        glds16(ga2 + k0, lA + 4096);
        glds16(gw1 + k0, lW);
        glds16(gw2 + k0, lW + 4096);
        __syncthreads();
        short8 af[4], wf[4];
#pragma unroll
        for (int i = 0; i < 4; i++) {
            const int ra = wm * 64 + i * 16 + low;
            af[i] = *(const short8*)&As[ra * 32 + (quad ^ ((ra >> 1) & 3)) * 8];
            const int rw = wn * 64 + i * 16 + low;
            wf[i] = *(const short8*)&Ws[rw * 32 + (quad ^ ((rw >> 1) & 3)) * 8];
        }
#pragma unroll
        for (int i = 0; i < 4; i++)
#pragma unroll
            for (int j = 0; j < 4; j++)
                acc[i][j] = __builtin_amdgcn_mfma_f32_16x16x32_bf16(
                    af[i], wf[j], acc[i][j], 0, 0, 0);
    }

#pragma unroll
    for (int i = 0; i < 4; i++) {
#pragma unroll
        for (int j = 0; j < 4; j++) {
            const int gc = n0 + wn * 64 + j * 16 + low;
            const float bv = bias[gc];
#pragma unroll
            for (int reg = 0; reg < 4; reg++) {
                const int gm = m0 + wm * 64 + i * 16 + quad * 4 + reg;
                const float val = acc[i][j][reg] + bv;
                if (MODE == 0) {
                    const int b_ = gm >> 11, npos = gm & 2047;
                    const int t3 = gc >> 10, rem = gc & 1023;
                    const int h = rem >> 6, d = rem & 63;
                    const int bh = b_ * 16 + h;
                    if (t3 == 0)
                        qb[((size_t)bh * 2048 + npos) * 64 + d] = f2bf(val);
                    else if (t3 == 1)
                        kb[((size_t)bh * 2048 + npos) * 64 + d] = f2bf(val);
                    else
                        vt[((size_t)bh * 64 + d) * 2048 + npos] = f2bf(val);
                } else {
                    outp[(size_t)gm * 1024 + gc] = val;
                }
            }
        }
    }
}

// ---------------------------------------------------------------------------
// RMSNorm + segmented RoPE, in place on bf16 q/k [bh][2048][64]. Wave per row.
// ---------------------------------------------------------------------------
__global__ __launch_bounds__(256) void norm_rope(
    unsigned short* __restrict__ q, unsigned short* __restrict__ k,
    const float* __restrict__ qw, const float* __restrict__ kw)
{
    const int gwave = blockIdx.x * 4 + (threadIdx.x >> 6);
    const int lane = threadIdx.x & 63;
    const int which = gwave >> 16;
    const int row = gwave & 65535;
    unsigned short* buf = which ? k : q;
    const float wval = which ? kw[lane] : qw[lane];

    float val = bf2f(buf[(size_t)row * 64 + lane]);
    float ss = val * val;
#pragma unroll
    for (int off = 32; off; off >>= 1) ss += __shfl_xor(ss, off);
    const float r = rsqrtf(ss * (1.0f / 64.0f) + 1e-6f);
    float nv = val * r * wval;

    const int npos = row & 2047;
    float outv = nv;
    if (npos < 1536) {  // wave-uniform
        const int p = (npos < 1024) ? npos : (npos - 1024);
        const int i = lane & 31;
        const float inv = exp2f(-(float)(2 * i) * (13.287712379549449f / 64.0f));
        const float ang = (float)p * inv;
        const float c = cosf(ang), s = sinf(ang);
        const float partner = __shfl_xor(nv, 32);
        outv = (lane < 32) ? (nv * c - partner * s) : (nv * c + partner * s);
    }
    buf[(size_t)row * 64 + lane] = outv == outv ? f2bf(outv) : 0;
}

// ---------------------------------------------------------------------------
// MFMA flash attention, static-M softmax (no running max/rescale; row-sum via
// MFMA against all-ones B). Block = 128 q-rows of one bh; 4 waves x 32 rows.
// 64-key tiles: K [64 keys][64 d] and V^T [64 d][64 keys] staged via glds with
// chunk^=(row&7) swizzle; P goes through padded LDS (C-layout -> A-layout).
// ---------------------------------------------------------------------------
__global__ __launch_bounds__(256) void flash_mfma(
    const unsigned short* __restrict__ qg, const unsigned short* __restrict__ kg,
    const unsigned short* __restrict__ vg, unsigned short* __restrict__ ao,
    const float* __restrict__ mb2p)
{
    __shared__ unsigned short Ks[64 * 64];
    __shared__ unsigned short Vs[64 * 64];
    __shared__ unsigned short Ps[4][32 * 72];   // per-wave, 72-elem rows (144B, 16B-aligned)

    const int tid = threadIdx.x;
    const int w = tid >> 6, l = tid & 63, quad = l >> 4, low = l & 15;
    const int bh = blockIdx.y, q0 = blockIdx.x * 128;
    const float MB2 = *mb2p;
    const float SCL = 0.125f * 1.4426950408889634f;

    // Q fragments (held in registers for the whole block)
    short8 qa[2][2];
#pragma unroll
    for (int mi = 0; mi < 2; mi++)
#pragma unroll
        for (int kh = 0; kh < 2; kh++) {
            const int qrow = q0 + w * 32 + mi * 16 + low;
            qa[mi][kh] = *(const short8*)(qg + ((size_t)bh * 2048 + qrow) * 64 +
                                          kh * 32 + quad * 8);
        }

    f32x4 o[2][4], lsum[2];
#pragma unroll
    for (int mi = 0; mi < 2; mi++) {
        lsum[mi] = (f32x4){0.f, 0.f, 0.f, 0.f};
#pragma unroll
        for (int db = 0; db < 4; db++) o[mi][db] = (f32x4){0.f, 0.f, 0.f, 0.f};
    }
    short8 ones;
#pragma unroll
    for (int j = 0; j < 8; j++) ones[j] = (short)0x3F80;  // bf16 1.0

    // staging source addresses (row&7 chunk swizzle keeps 128B-row b128 reads 2-way)
    const int kr1 = tid >> 3, kp1 = tid & 7, kc1 = kp1 ^ (kr1 & 7);
    const int kr2 = kr1 + 32, kc2 = kp1 ^ (kr2 & 7);
    const unsigned short* gk1 = kg + ((size_t)bh * 2048 + kr1) * 64 + kc1 * 8;
    const unsigned short* gk2 = kg + ((size_t)bh * 2048 + kr2) * 64 + kc2 * 8;
    const unsigned short* gv1 = vg + ((size_t)bh * 64 + kr1) * 2048 + kc1 * 8;
    const unsigned short* gv2 = vg + ((size_t)bh * 64 + kr2) * 2048 + kc2 * 8;
    char* lK = (char*)Ks + (w << 10);
    char* lV = (char*)Vs + (w << 10);
    unsigned short* myP = Ps[w];

    for (int kt = 0; kt < 32; kt++) {
        const size_t ko = (size_t)kt * 64 * 64;  // K advances 64 rows of 64
        const int vo = kt * 64;                  // V^T advances 64 cols
        __syncthreads();
        glds16(gk1 + ko, lK);
        glds16(gk2 + ko, lK + 4096);
        glds16(gv1 + vo, lV);
        glds16(gv2 + vo, lV + 4096);
        __syncthreads();

        // scores + exp -> P (bf16, padded LDS)
#pragma unroll
        for (int kb = 0; kb < 4; kb++) {
            const int krow = kb * 16 + low;
            const short8 kf0 = *(const short8*)&Ks[krow * 64 + ((0 + quad) ^ (krow & 7)) * 8];
            const short8 kf1 = *(const short8*)&Ks[krow * 64 + ((4 + quad) ^ (krow & 7)) * 8];
#pragma unroll
            for (int mi = 0; mi < 2; mi++) {
                f32x4 s = __builtin_amdgcn_mfma_f32_16x16x32_bf16(
                    qa[mi][0], kf0, (f32x4){0.f, 0.f, 0.f, 0.f}, 0, 0, 0);
                s = __builtin_amdgcn_mfma_f32_16x16x32_bf16(qa[mi][1], kf1, s, 0, 0, 0);
#pragma unroll
                for (int reg = 0; reg < 4; reg++) {
                    const float p = exp2f(fmaf(s[reg], SCL, -MB2));
                    const int qr = mi * 16 + quad * 4 + reg;
                    myP[qr * 72 + kb * 16 + low] = f2bf(p);
                }
            }
        }

        // PV + row-sum (same wave wrote myP; DS ops are in-order per wave)
#pragma unroll
        for (int mi = 0; mi < 2; mi++) {
            short8 pa[2];
#pragma unroll
            for (int kh = 0; kh < 2; kh++)
                pa[kh] = *(const short8*)&myP[(mi * 16 + low) * 72 + kh * 32 + quad * 8];
            lsum[mi] = __builtin_amdgcn_mfma_f32_16x16x32_bf16(pa[0], ones, lsum[mi], 0, 0, 0);
            lsum[mi] = __builtin_amdgcn_mfma_f32_16x16x32_bf16(pa[1], ones, lsum[mi], 0, 0, 0);
#pragma unroll
            for (int db = 0; db < 4; db++) {
                const int d = db * 16 + low;
                const short8 vf0 = *(const short8*)&Vs[d * 64 + ((0 + quad) ^ (d & 7)) * 8];
                const short8 vf1 = *(const short8*)&Vs[d * 64 + ((4 + quad) ^ (d & 7)) * 8];
                o[mi][db] = __builtin_amdgcn_mfma_f32_16x16x32_bf16(pa[0], vf0, o[mi][db], 0, 0, 0);
                o[mi][db] = __builtin_amdgcn_mfma_f32_16x16x32_bf16(pa[1], vf1, o[mi][db], 0, 0, 0);
            }
        }
    }

    // epilogue: O/l -> ao[b][n][h*64+d] bf16
    const int b_ = bh >> 4, h = bh & 15;
#pragma unroll
    for (int mi = 0; mi < 2; mi++) {
        float inv[4];
#pragma unroll
        for (int reg = 0; reg < 4; reg++) inv[reg] = 1.0f / lsum[mi][reg];
#pragma unroll
        for (int db = 0; db < 4; db++)
#pragma unroll
            for (int reg = 0; reg < 4; reg++) {
                const int n = q0 + w * 32 + mi * 16 + quad * 4 + reg;
                ao[((size_t)(b_ * 2048 + n)) * 1024 + h * 64 + db * 16 + low] =
                    f2bf(o[mi][db][reg] * inv[reg]);
            }
    }
}

// ---------------------------------------------------------------------------
extern "C" void kernel_launch(void* const* d_in, const int* in_sizes, int n_in,
                              void* d_out, int out_size, void* d_ws, size_t ws_size,
                              hipStream_t stream)
{
    const float* x      = (const float*)d_in[0];
    const float* qkv_w  = (const float*)d_in[1];
    const float* qkv_b  = (const float*)d_in[2];
    const float* qn_w   = (const float*)d_in[3];
    const float* kn_w   = (const float*)d_in[4];
    const float* proj_w = (const float*)d_in[5];
    const float* proj_b = (const float*)d_in[6];

    // ws layout (bytes):
    char* base = (char*)d_ws;
    float* mb2          = (float*)base;                                 // 256
    unsigned short* xb  = (unsigned short*)(base + 256);                // 8,388,608
    unsigned short* qwb = xb  + 4194304;                                // 6,291,456
    unsigned short* pwb = qwb + 3145728;                                // 2,097,152
    unsigned short* qb  = pwb + 1048576;                                // 8,388,608
    unsigned short* kb  = qb  + 4194304;                                // 8,388,608
    unsigned short* vt  = kb  + 4194304;                                // 8,388,608
    unsigned short* ao  = vt  + 4194304;                                // 8,388,608
    // total ~50.3 MB

    wmax_k<<<1, 64, 0, stream>>>(qn_w, kn_w, mb2);
    cvt_bf16<<<4096, 256, 0, stream>>>(x, xb, 1048576);
    cvt_bf16<<<3072, 256, 0, stream>>>(qkv_w, qwb, 786432);
    cvt_bf16<<<1024, 256, 0, stream>>>(proj_w, pwb, 262144);

    // QKV projection -> q,k bf16 [bh][n][64]; v bf16 transposed [bh][64][n]
    gemm_mfma<0><<<dim3(24, 32), 256, 0, stream>>>(
        xb, qwb, qkv_b, qb, kb, vt, nullptr, 1024);

    // RMSNorm + segmented RoPE in place on q,k
    norm_rope<<<32768, 256, 0, stream>>>(qb, kb, qn_w, kn_w);

    // attention -> ao bf16 [b][n][1024]
    flash_mfma<<<dim3(16, 32), 256, 0, stream>>>(qb, kb, vt, ao, mb2);

    // output projection -> d_out fp32
    gemm_mfma<1><<<dim3(8, 32), 256, 0, stream>>>(
        ao, pwb, proj_b, nullptr, nullptr, nullptr, (float*)d_out, 1024);
}

// Round 4
// 216.150 us; speedup vs baseline: 6.7433x; 1.2118x over previous
//
#include <hip/hip_runtime.h>

typedef __attribute__((ext_vector_type(8))) short short8;
typedef __attribute__((ext_vector_type(4))) float f32x4;

__device__ __forceinline__ float bf2f(unsigned short u) {
    union { unsigned int i; float f; } c; c.i = ((unsigned int)u) << 16; return c.f;
}
__device__ __forceinline__ unsigned short f2bf(float f) {   // RNE
    union { float f; unsigned int i; } c; c.f = f;
    unsigned int u = c.i;
    return (unsigned short)((u + 0x7fffu + ((u >> 16) & 1u)) >> 16);
}

// async global->LDS, 16B per lane. LDS dest = wave-uniform base + lane*16.
__device__ __forceinline__ void glds16(const void* g, void* l) {
    __builtin_amdgcn_global_load_lds(
        (const __attribute__((address_space(1))) unsigned int*)g,
        (__attribute__((address_space(3))) unsigned int*)l, 16, 0, 0);
}

// ---------------------------------------------------------------------------
// prep: fp32->bf16 for x / qkv_w / proj_w, plus softmax bound MB2.
// grid 8193 x 256. Blocks [0,4096) x, [4096,7168) qkv_w, [7168,8192) proj_w,
// block 8192 computes MB2 = 8*max|qn|*max|kn|*log2(e).
// ---------------------------------------------------------------------------
__global__ __launch_bounds__(256) void prep(
    const float* __restrict__ x, const float* __restrict__ qkv_w,
    const float* __restrict__ proj_w,
    const float* __restrict__ qn_w, const float* __restrict__ kn_w,
    unsigned short* __restrict__ xb, unsigned short* __restrict__ qwb,
    unsigned short* __restrict__ pwb, float* __restrict__ mb2)
{
    const int b = blockIdx.x, tid = threadIdx.x;
    const float* src; unsigned short* dst; int i;
    if (b < 4096)      { src = x;      dst = xb;  i = b * 256 + tid; }
    else if (b < 7168) { src = qkv_w;  dst = qwb; i = (b - 4096) * 256 + tid; }
    else if (b < 8192) { src = proj_w; dst = pwb; i = (b - 7168) * 256 + tid; }
    else {
        if (tid < 64) {
            float a = fabsf(qn_w[tid]), bb = fabsf(kn_w[tid]);
#pragma unroll
            for (int off = 32; off; off >>= 1) {
                a = fmaxf(a, __shfl_xor(a, off));
                bb = fmaxf(bb, __shfl_xor(bb, off));
            }
            if (tid == 0) *mb2 = 8.0f * a * bb * 1.4426950408889634f;
        }
        return;
    }
    float4 v = ((const float4*)src)[i];
    ushort4 o;
    o.x = f2bf(v.x); o.y = f2bf(v.y); o.z = f2bf(v.z); o.w = f2bf(v.w);
    ((ushort4*)dst)[i] = o;
}

// ---------------------------------------------------------------------------
// QKV GEMM (NT) + fused bias + RMSNorm + segmented RoPE epilogue.
// C[m][n] = sum_k A[m][k]*W[n][k]; 128x128 tile, BK=32, 4 waves 2x2.
// Each wave's 64-col half = exactly one head => a full (npos,h,d=0..63) row
// lives in 16 lanes x 4 regs: RMS via 4 shfl_xor; RoPE partner d^32 = reg j^2.
// q,k -> bf16 [bh][n][64]; v -> bf16 transposed [bh][64][n].
// ---------------------------------------------------------------------------
__global__ __launch_bounds__(256) void gemm_qkv(
    const unsigned short* __restrict__ A,
    const unsigned short* __restrict__ W,
    const float* __restrict__ bias,
    const float* __restrict__ qn_w, const float* __restrict__ kn_w,
    unsigned short* __restrict__ qb, unsigned short* __restrict__ kb,
    unsigned short* __restrict__ vt)
{
    __shared__ unsigned short As[128 * 32];
    __shared__ unsigned short Ws[128 * 32];
    const int tid = threadIdx.x;
    const int w = tid >> 6, l = tid & 63, quad = l >> 4, low = l & 15;
    const int m0 = blockIdx.y * 128, n0 = blockIdx.x * 128;
    const int wm = w >> 1, wn = w & 1;
    const int K = 1024;

    f32x4 acc[4][4];
#pragma unroll
    for (int i = 0; i < 4; i++)
#pragma unroll
        for (int j = 0; j < 4; j++) acc[i][j] = (f32x4){0.f, 0.f, 0.f, 0.f};

    const int r1 = tid >> 2, p1 = tid & 3;
    const int c1 = p1 ^ ((r1 >> 1) & 3);
    const int r2 = r1 + 64;
    const int c2 = p1 ^ ((r2 >> 1) & 3);
    const unsigned short* ga1 = A + (size_t)(m0 + r1) * K + c1 * 8;
    const unsigned short* ga2 = A + (size_t)(m0 + r2) * K + c2 * 8;
    const unsigned short* gw1 = W + (size_t)(n0 + r1) * K + c1 * 8;
    const unsigned short* gw2 = W + (size_t)(n0 + r2) * K + c2 * 8;
    char* lA = (char*)As + (w << 10);
    char* lW = (char*)Ws + (w << 10);

    for (int k0 = 0; k0 < K; k0 += 32) {
        __syncthreads();
        glds16(ga1 + k0, lA);
        glds16(ga2 + k0, lA + 4096);
        glds16(gw1 + k0, lW);
        glds16(gw2 + k0, lW + 4096);
        __syncthreads();
        short8 af[4], wf[4];
#pragma unroll
        for (int i = 0; i < 4; i++) {
            const int ra = wm * 64 + i * 16 + low;
            af[i] = *(const short8*)&As[ra * 32 + (quad ^ ((ra >> 1) & 3)) * 8];
            const int rw = wn * 64 + i * 16 + low;
            wf[i] = *(const short8*)&Ws[rw * 32 + (quad ^ ((rw >> 1) & 3)) * 8];
        }
#pragma unroll
        for (int i = 0; i < 4; i++)
#pragma unroll
            for (int j = 0; j < 4; j++)
                acc[i][j] = __builtin_amdgcn_mfma_f32_16x16x32_bf16(
                    af[i], wf[j], acc[i][j], 0, 0, 0);
    }

    // ---- fused epilogue ----
    const int colbase = n0 + wn * 64;          // 64-aligned => wave-uniform head
    const int t3 = colbase >> 10;              // 0=q, 1=k, 2=v
    const int hh = (colbase & 1023) >> 6;
    float wv4[4] = {0, 0, 0, 0}, invA = 0.f, invB = 0.f;
    if (t3 < 2) {
        const float* nw = (t3 == 0) ? qn_w : kn_w;
#pragma unroll
        for (int j = 0; j < 4; j++) wv4[j] = nw[j * 16 + low];
        const float c0 = -2.0f * 13.287712379549449f / 64.0f;  // -2*log2(1e4)/64
        invA = exp2f(c0 * (float)low);          // freq for i = low      (j=0,2)
        invB = exp2f(c0 * (float)(16 + low));   // freq for i = 16+low   (j=1,3)
    }
    unsigned short* dqk = (t3 == 0) ? qb : kb;

#pragma unroll
    for (int i = 0; i < 4; i++) {
#pragma unroll
        for (int reg = 0; reg < 4; reg++) {
            const int gm = m0 + wm * 64 + i * 16 + quad * 4 + reg;
            const int b_ = gm >> 11, npos = gm & 2047;
            float v[4];
#pragma unroll
            for (int j = 0; j < 4; j++)
                v[j] = acc[i][j][reg] + bias[colbase + j * 16 + low];
            if (t3 == 2) {
#pragma unroll
                for (int j = 0; j < 4; j++)
                    vt[((size_t)(b_ * 16 + hh) * 64 + j * 16 + low) * 2048 + npos] =
                        f2bf(v[j]);
            } else {
                float ss = v[0]*v[0] + v[1]*v[1] + v[2]*v[2] + v[3]*v[3];
                ss += __shfl_xor(ss, 1); ss += __shfl_xor(ss, 2);
                ss += __shfl_xor(ss, 4); ss += __shfl_xor(ss, 8);
                const float r = rsqrtf(ss * (1.0f / 64.0f) + 1e-6f);
                float nv[4];
#pragma unroll
                for (int j = 0; j < 4; j++) nv[j] = v[j] * r * wv4[j];
                float o0, o1, o2, o3;
                if (npos < 1536) {
                    const float p = (float)((npos < 1024) ? npos : (npos - 1024));
                    float sA, cA, sB, cB;
                    __sincosf(p * invA, &sA, &cA);
                    __sincosf(p * invB, &sB, &cB);
                    o0 = nv[0] * cA - nv[2] * sA;
                    o1 = nv[1] * cB - nv[3] * sB;
                    o2 = nv[2] * cA + nv[0] * sA;
                    o3 = nv[3] * cB + nv[1] * sB;
                } else { o0 = nv[0]; o1 = nv[1]; o2 = nv[2]; o3 = nv[3]; }
                unsigned short* drow =
                    dqk + ((size_t)(b_ * 16 + hh) * 2048 + npos) * 64 + low;
                drow[0]  = f2bf(o0);
                drow[16] = f2bf(o1);
                drow[32] = f2bf(o2);
                drow[48] = f2bf(o3);
            }
        }
    }
}

// ---------------------------------------------------------------------------
// MFMA flash attention, static-M softmax. Block = 64 q-rows of one bh;
// 4 waves x 16 rows; grid (32,32) = 1024 blocks (4/CU). 64-key tiles.
// QK^T computed TRANSPOSED (mfma(kf,qa) -> S^T) so each lane's 4 score regs
// are 4 consecutive keys of its own q-row: exp'd P packs via v_perm into one
// ds_write_b64. P read back as A-frag (row-major, pad 72). Row-sum via MFMA
// against all-ones B.
// ---------------------------------------------------------------------------
__global__ __launch_bounds__(256) void flash_mfma(
    const unsigned short* __restrict__ qg, const unsigned short* __restrict__ kg,
    const unsigned short* __restrict__ vg, unsigned short* __restrict__ ao,
    const float* __restrict__ mb2p)
{
    __shared__ unsigned short Ks[64 * 64];
    __shared__ unsigned short Vs[64 * 64];
    __shared__ unsigned short Ps[4][16 * 72];

    const int tid = threadIdx.x;
    const int w = tid >> 6, l = tid & 63, quad = l >> 4, low = l & 15;
    const int bh = blockIdx.y, q0 = blockIdx.x * 64;
    const float MB2 = *mb2p;
    const float SCL = 0.125f * 1.4426950408889634f;

    short8 qa[2];
#pragma unroll
    for (int kh = 0; kh < 2; kh++) {
        const int qrow = q0 + w * 16 + low;
        qa[kh] = *(const short8*)(qg + ((size_t)bh * 2048 + qrow) * 64 +
                                  kh * 32 + quad * 8);
    }

    f32x4 o[4], lsum = (f32x4){0.f, 0.f, 0.f, 0.f};
#pragma unroll
    for (int db = 0; db < 4; db++) o[db] = (f32x4){0.f, 0.f, 0.f, 0.f};
    short8 ones;
#pragma unroll
    for (int j = 0; j < 8; j++) ones[j] = (short)0x3F80;  // bf16 1.0

    const int kr1 = tid >> 3, kp1 = tid & 7, kc1 = kp1 ^ (kr1 & 7);
    const int kr2 = kr1 + 32, kc2 = kp1 ^ (kr2 & 7);
    const unsigned short* gk1 = kg + ((size_t)bh * 2048 + kr1) * 64 + kc1 * 8;
    const unsigned short* gk2 = kg + ((size_t)bh * 2048 + kr2) * 64 + kc2 * 8;
    const unsigned short* gv1 = vg + ((size_t)bh * 64 + kr1) * 2048 + kc1 * 8;
    const unsigned short* gv2 = vg + ((size_t)bh * 64 + kr2) * 2048 + kc2 * 8;
    char* lK = (char*)Ks + (w << 10);
    char* lV = (char*)Vs + (w << 10);
    unsigned short* myP = Ps[w];

    for (int kt = 0; kt < 32; kt++) {
        const size_t ko = (size_t)kt * 4096;   // K: 64 rows x 64
        const int vo = kt * 64;                // V^T: 64 cols
        __syncthreads();
        glds16(gk1 + ko, lK);
        glds16(gk2 + ko, lK + 4096);
        glds16(gv1 + vo, lV);
        glds16(gv2 + vo, lV + 4096);
        __syncthreads();

        // S^T = K . Q^T : lane holds key = kb*16+quad*4+reg, qrow = low
#pragma unroll
        for (int kb = 0; kb < 4; kb++) {
            const int krow = kb * 16 + low;
            const short8 kf0 = *(const short8*)&Ks[krow * 64 + (quad ^ (krow & 7)) * 8];
            const short8 kf1 = *(const short8*)&Ks[krow * 64 + ((4 + quad) ^ (krow & 7)) * 8];
            f32x4 s = __builtin_amdgcn_mfma_f32_16x16x32_bf16(
                kf0, qa[0], (f32x4){0.f, 0.f, 0.f, 0.f}, 0, 0, 0);
            s = __builtin_amdgcn_mfma_f32_16x16x32_bf16(kf1, qa[1], s, 0, 0, 0);
            unsigned int pb[4];
#pragma unroll
            for (int reg = 0; reg < 4; reg++) {
                union { float f; unsigned int u; } cc;
                cc.f = exp2f(fmaf(s[reg], SCL, -MB2));
                pb[reg] = cc.u;
            }
            // truncating bf16 pack: [p0,p1] and [p2,p3]
            const unsigned int u0 = __builtin_amdgcn_perm(pb[1], pb[0], 0x07060302u);
            const unsigned int u1 = __builtin_amdgcn_perm(pb[3], pb[2], 0x07060302u);
            *(uint2*)&myP[low * 72 + kb * 16 + quad * 4] = make_uint2(u0, u1);
        }

        // PV + row-sum (per-wave P region; DS in-order per wave)
        short8 pa[2];
#pragma unroll
        for (int kh = 0; kh < 2; kh++)
            pa[kh] = *(const short8*)&myP[low * 72 + kh * 32 + quad * 8];
        lsum = __builtin_amdgcn_mfma_f32_16x16x32_bf16(pa[0], ones, lsum, 0, 0, 0);
        lsum = __builtin_amdgcn_mfma_f32_16x16x32_bf16(pa[1], ones, lsum, 0, 0, 0);
#pragma unroll
        for (int db = 0; db < 4; db++) {
            const int d = db * 16 + low;
            const short8 vf0 = *(const short8*)&Vs[d * 64 + (quad ^ (d & 7)) * 8];
            const short8 vf1 = *(const short8*)&Vs[d * 64 + ((4 + quad) ^ (d & 7)) * 8];
            o[db] = __builtin_amdgcn_mfma_f32_16x16x32_bf16(pa[0], vf0, o[db], 0, 0, 0);
            o[db] = __builtin_amdgcn_mfma_f32_16x16x32_bf16(pa[1], vf1, o[db], 0, 0, 0);
        }
    }

    const int b_ = bh >> 4, h = bh & 15;
    float inv[4];
#pragma unroll
    for (int reg = 0; reg < 4; reg++) inv[reg] = 1.0f / lsum[reg];
#pragma unroll
    for (int db = 0; db < 4; db++)
#pragma unroll
        for (int reg = 0; reg < 4; reg++) {
            const int n = q0 + w * 16 + quad * 4 + reg;
            ao[((size_t)(b_ * 2048 + n)) * 1024 + h * 64 + db * 16 + low] =
                f2bf(o[db][reg] * inv[reg]);
        }
}

// ---------------------------------------------------------------------------
// Output projection: out[m][n] = sum_k A[m][k]*W[n][k] + bias[n], fp32 out.
// 64x128 tile, BK=32 -> grid (8,64) = 512 blocks (2/CU).
// ---------------------------------------------------------------------------
__global__ __launch_bounds__(256) void gemm_out(
    const unsigned short* __restrict__ A,
    const unsigned short* __restrict__ W,
    const float* __restrict__ bias,
    float* __restrict__ outp)
{
    __shared__ unsigned short As[64 * 32];
    __shared__ unsigned short Ws[128 * 32];
    const int tid = threadIdx.x;
    const int w = tid >> 6, l = tid & 63, quad = l >> 4, low = l & 15;
    const int m0 = blockIdx.y * 64, n0 = blockIdx.x * 128;
    const int wm = w >> 1, wn = w & 1;
    const int K = 1024;

    f32x4 acc[2][4];
#pragma unroll
    for (int i = 0; i < 2; i++)
#pragma unroll
        for (int j = 0; j < 4; j++) acc[i][j] = (f32x4){0.f, 0.f, 0.f, 0.f};

    const int r1 = tid >> 2, p1 = tid & 3;
    const int c1 = p1 ^ ((r1 >> 1) & 3);
    const int r2 = r1 + 64;
    const int c2 = p1 ^ ((r2 >> 1) & 3);
    const unsigned short* ga = A + (size_t)(m0 + r1) * K + c1 * 8;
    const unsigned short* gw1 = W + (size_t)(n0 + r1) * K + c1 * 8;
    const unsigned short* gw2 = W + (size_t)(n0 + r2) * K + c2 * 8;
    char* lA = (char*)As + (w << 10);
    char* lW = (char*)Ws + (w << 10);

    for (int k0 = 0; k0 < K; k0 += 32) {
        __syncthreads();
        glds16(ga + k0, lA);
        glds16(gw1 + k0, lW);
        glds16(gw2 + k0, lW + 4096);
        __syncthreads();
        short8 af[2], wf[4];
#pragma unroll
        for (int i = 0; i < 2; i++) {
            const int ra = wm * 32 + i * 16 + low;
            af[i] = *(const short8*)&As[ra * 32 + (quad ^ ((ra >> 1) & 3)) * 8];
        }
#pragma unroll
        for (int j = 0; j < 4; j++) {
            const int rw = wn * 64 + j * 16 + low;
            wf[j] = *(const short8*)&Ws[rw * 32 + (quad ^ ((rw >> 1) & 3)) * 8];
        }
#pragma unroll
        for (int i = 0; i < 2; i++)
#pragma unroll
            for (int j = 0; j < 4; j++)
                acc[i][j] = __builtin_amdgcn_mfma_f32_16x16x32_bf16(
                    af[i], wf[j], acc[i][j], 0, 0, 0);
    }

#pragma unroll
    for (int i = 0; i < 2; i++)
#pragma unroll
        for (int j = 0; j < 4; j++) {
            const int gc = n0 + wn * 64 + j * 16 + low;
            const float bv = bias[gc];
#pragma unroll
            for (int reg = 0; reg < 4; reg++) {
                const int gm = m0 + wm * 32 + i * 16 + quad * 4 + reg;
                outp[(size_t)gm * 1024 + gc] = acc[i][j][reg] + bv;
            }
        }
}

// ---------------------------------------------------------------------------
extern "C" void kernel_launch(void* const* d_in, const int* in_sizes, int n_in,
                              void* d_out, int out_size, void* d_ws, size_t ws_size,
                              hipStream_t stream)
{
    const float* x      = (const float*)d_in[0];
    const float* qkv_w  = (const float*)d_in[1];
    const float* qkv_b  = (const float*)d_in[2];
    const float* qn_w   = (const float*)d_in[3];
    const float* kn_w   = (const float*)d_in[4];
    const float* proj_w = (const float*)d_in[5];
    const float* proj_b = (const float*)d_in[6];

    char* base = (char*)d_ws;
    float* mb2          = (float*)base;                                 // 256 B
    unsigned short* xb  = (unsigned short*)(base + 256);                // 8 MB
    unsigned short* qwb = xb  + 4194304;                                // 6 MB
    unsigned short* pwb = qwb + 3145728;                                // 2 MB
    unsigned short* qb  = pwb + 1048576;                                // 8 MB
    unsigned short* kb  = qb  + 4194304;                                // 8 MB
    unsigned short* vt  = kb  + 4194304;                                // 8 MB
    unsigned short* ao  = vt  + 4194304;                                // 8 MB

    // 0) bf16 casts + softmax bound (single launch)
    prep<<<8193, 256, 0, stream>>>(x, qkv_w, proj_w, qn_w, kn_w, xb, qwb, pwb, mb2);

    // 1) QKV projection + fused RMSNorm + segmented RoPE
    gemm_qkv<<<dim3(24, 32), 256, 0, stream>>>(xb, qwb, qkv_b, qn_w, kn_w,
                                               qb, kb, vt);

    // 2) attention -> ao bf16 [b][n][1024]
    flash_mfma<<<dim3(32, 32), 256, 0, stream>>>(qb, kb, vt, ao, mb2);

    // 3) output projection -> d_out fp32
    gemm_out<<<dim3(8, 64), 256, 0, stream>>>(ao, pwb, proj_b, (float*)d_out);
}